// Round 12
// baseline (595.492 us; speedup 1.0000x reference)
//
#include <hip/hip_runtime.h>
#include <math.h>

// Problem constants
#define QN 4096
#define MN 65536
#define DN 384
#define CN 128
#define NCHUNK 64                 // m-chunks
#define MROWS_PER_CHUNK (MN / NCHUNK)   // 1024
#define MT_PER (MROWS_PER_CHUNK / 64)   // 16 m-tiles (64 rows) per block
#define FRAG_B 2048                     // one fragment-major block: 64 lanes x 32B
#define GSTRIDE (3 * FRAG_B)            // bytes per 16-row group (3 kc)
#define TSTRIDE (4 * GSTRIDE)           // bytes per 64-row tile = 24576

typedef __attribute__((ext_vector_type(8))) int i32x8;
typedef __attribute__((ext_vector_type(4))) int i32x4;
typedef __attribute__((ext_vector_type(4))) float f32x4;

__device__ __forceinline__ void async16(const void* g, void* l) {
  __builtin_amdgcn_global_load_lds(
      (const __attribute__((address_space(1))) unsigned int*)g,
      (__attribute__((address_space(3))) unsigned int*)l, 16, 0, 0);
}

// ------- Kernel A: L2-normalize rows (q then m) -> fp8 --------------------
// q-rows: linear layout (consumed by the GEMM's LDS A-stage).
// m-rows: FRAGMENT-MAJOR layout — the exact per-lane register image of the
// MFMA B-operand (see R11 notes). GEMM B loads become perfectly coalesced
// global->VGPR; R11 verified (conflicts 7.08M -> 786K = A-stage only).
__global__ __launch_bounds__(256) void nrm_kernel(const float* __restrict__ qe,
                                                  const float* __restrict__ me,
                                                  unsigned char* __restrict__ yq,
                                                  unsigned char* __restrict__ ym) {
  const int row = blockIdx.x * 4 + (threadIdx.x >> 6);
  const int lane = threadIdx.x & 63;
  const float* xr = (row < QN) ? qe + (size_t)row * DN
                               : me + (size_t)(row - QN) * DN;
  float2 v[3];
  float ss = 0.f;
#pragma unroll
  for (int i = 0; i < 3; ++i) {
    v[i] = *(const float2*)&xr[lane * 2 + i * 128];
    ss += v[i].x * v[i].x + v[i].y * v[i].y;
  }
#pragma unroll
  for (int m = 1; m < 64; m <<= 1) ss += __shfl_xor(ss, m);
  const float scale = 1.0f / fmaxf(sqrtf(ss), 1e-8f);
  if (row < QN) {
    unsigned short* yw = (unsigned short*)(yq + (size_t)row * DN);
#pragma unroll
    for (int i = 0; i < 3; ++i) {
      const int p = __builtin_amdgcn_cvt_pk_fp8_f32(v[i].x * scale,
                                                    v[i].y * scale, 0, false);
      yw[lane + i * 64] = (unsigned short)(p & 0xffff);
    }
  } else {
    const int mr = row - QN;
    const int g = mr >> 4, r15 = mr & 15;
    const int fl = ((lane >> 4) << 4) + r15;   // fragment lane index
    unsigned short* yw = (unsigned short*)ym;
#pragma unroll
    for (int i = 0; i < 3; ++i) {
      const int p = __builtin_amdgcn_cvt_pk_fp8_f32(v[i].x * scale,
                                                    v[i].y * scale, 0, false);
      yw[((size_t)(g * 3 + i) * 64 + fl) * 16 + (lane & 15)] =
          (unsigned short)(p & 0xffff);
    }
  }
}

// ------- Kernel B: MX-fp8 GEMM, barrier-free + register double-buffer ------
// R12: R11 (84.1 µs, MfmaUtil 54%) showed per-visit 1575 cyc = load-wait 745
// + MFMA 830, serialized WITHIN each wave (no buffering). Add cross-tile
// register dbuf — affordable now that the loop is lean (R4's spill came from
// the LDS machinery): afr 96 + bfrA 48 + bfrB 48 + acc 16 (ct-split fold
// halves it) + rmax 16 + ptrs ~= 242 <= 256 @ 2 waves/SIMD.
// Steady state: MFMA(A) | issue A(mt+2) | vmcnt(12) [B ready] | MFMA(B) |
// issue B(mt+3) | vmcnt(12) [A ready]. Every tile's loads get a full MFMA
// phase (~830 cyc) to land; no wait precedes an MFMA cluster. Backend
// auto-inserts exact dep waits (correctness) regardless of counted asm.
__global__ __launch_bounds__(256, 2) void gemm_max_kernel(
    const unsigned char* __restrict__ qn8, const unsigned char* __restrict__ mn8,
    float* __restrict__ pmax) {
  __shared__ unsigned char As[128 * DN];   // 48 KB: A staging only
  __shared__ float smax[2][128];

  const int tid = threadIdx.x;
  const int wave = tid >> 6, lane = tid & 63;
  const int wr = wave >> 1, wc = wave & 1;   // waves: 2x2 over 128q x 64m
  const int quad = lane >> 4, l16 = lane & 15;
  const int r7 = l16 & 7;

  // --- XCD-partitioned bijective swizzle (HW assigns XCD = linear id % 8) ---
  const int bid = blockIdx.y * gridDim.x + blockIdx.x;  // linear dispatch id
  const int xcd = bid & 7;
  const int j = bid >> 3;                    // 0..255 within this XCD
  const int ychunk = (xcd << 3) | (j >> 5);  // 8 m-chunks per XCD
  const int qrow0 = (j & 31) * 128;          // x sweeps fastest
  const int mchunk0 = ychunk * MROWS_PER_CHUNK;

  float rmax[16];
#pragma unroll
  for (int i = 0; i < 16; ++i) rmax[i] = -3.0e38f;

  // ---- stage A tile (128x384 = 48 KB) once, hoist fragments to registers --
  {
    const unsigned char* abase = qn8 + (size_t)qrow0 * DN;
#pragma unroll
    for (int i = 0; i < 12; ++i) {
      const int ci = i * 256 + tid;               // 16B chunk 0..3071
      const int row = ci / 24;
      const int jj = ci - row * 24;
      const int gj = (jj & 24) | ((jj ^ row) & 7);  // XOR-swizzled source chunk
      async16(abase + row * DN + gj * 16, &As[(i * 256 + wave * 64) * 16]);
    }
  }
  __syncthreads();  // full drain: A staged
  i32x8 afr[3][4];
#pragma unroll
  for (int kc = 0; kc < 3; ++kc)
#pragma unroll
    for (int rt = 0; rt < 4; ++rt) {
      const unsigned char* p = &As[(wr * 64 + rt * 16 + l16) * DN];
      i32x4 lo = *(const i32x4*)&p[(kc * 8 + ((quad * 2 + 0) ^ r7)) * 16];
      i32x4 hi = *(const i32x4*)&p[(kc * 8 + ((quad * 2 + 1) ^ r7)) * 16];
      afr[kc][rt][0] = lo[0]; afr[kc][rt][1] = lo[1];
      afr[kc][rt][2] = lo[2]; afr[kc][rt][3] = lo[3];
      afr[kc][rt][4] = hi[0]; afr[kc][rt][5] = hi[1];
      afr[kc][rt][6] = hi[2]; afr[kc][rt][7] = hi[3];
    }
  // no further LDS use until epilogue; NO barriers in the main loop

  // --- per-wave fragment-major B pointers (ct=0 -> group g0, ct=1 -> g0+1) -
  const int g0 = (mchunk0 >> 4) + wc * 2;
  const unsigned char* bpA0 = mn8 + ((size_t)g0 * 3 * 64 + lane) * 32;
  const unsigned char* bpA1 = bpA0 + GSTRIDE;
  const unsigned char* bpB0 = bpA0 + TSTRIDE;
  const unsigned char* bpB1 = bpA1 + TSTRIDE;

#define LOADB(BFR, P0, P1)                                  \
  do {                                                      \
    _Pragma("unroll") for (int kc = 0; kc < 3; ++kc) {      \
      BFR[kc][0] = *(const i32x8*)((P0) + kc * FRAG_B);     \
      BFR[kc][1] = *(const i32x8*)((P1) + kc * FRAG_B);     \
    }                                                       \
  } while (0)

#define COMPUTE_TILE(BFR)                                                     \
  do {                                                                        \
    _Pragma("unroll") for (int ct = 0; ct < 2; ++ct) {                        \
      f32x4 acc[4];                                                           \
      _Pragma("unroll") for (int rt = 0; rt < 4; ++rt)                        \
          acc[rt] = (f32x4){0.f, 0.f, 0.f, 0.f};                              \
      __builtin_amdgcn_s_setprio(1);                                          \
      _Pragma("unroll") for (int kc = 0; kc < 3; ++kc)                        \
          _Pragma("unroll") for (int rt = 0; rt < 4; ++rt)                    \
              acc[rt] = __builtin_amdgcn_mfma_scale_f32_16x16x128_f8f6f4(     \
                  afr[kc][rt], BFR[kc][ct], acc[rt], 0, 0, 0, 0x7f7f7f7f, 0,  \
                  0x7f7f7f7f);                                                \
      __builtin_amdgcn_s_setprio(0);                                          \
      _Pragma("unroll") for (int rt = 0; rt < 4; ++rt)                        \
          _Pragma("unroll") for (int r = 0; r < 4; ++r)                       \
              rmax[rt * 4 + r] = fmaxf(rmax[rt * 4 + r], acc[rt][r]);         \
    }                                                                         \
  } while (0)

  i32x8 bfrA[3][2], bfrB[3][2];
  // prologue: tiles 0 (->bfrA) and 1 (->bfrB) in flight; drain tile 0
  LOADB(bfrA, bpA0, bpA1);
  bpA0 += 2 * TSTRIDE; bpA1 += 2 * TSTRIDE;
  LOADB(bfrB, bpB0, bpB1);
  bpB0 += 2 * TSTRIDE; bpB1 += 2 * TSTRIDE;
  asm volatile("s_waitcnt vmcnt(12)" ::: "memory");
  __builtin_amdgcn_sched_barrier(0);

#pragma unroll 1
  for (int mt = 0; mt < MT_PER; mt += 2) {
    COMPUTE_TILE(bfrA);                      // tile mt; B(mt+1) lands under it
    if (mt + 2 < MT_PER) {
      LOADB(bfrA, bpA0, bpA1);               // issue tile mt+2
      bpA0 += 2 * TSTRIDE; bpA1 += 2 * TSTRIDE;
      asm volatile("s_waitcnt vmcnt(12)" ::: "memory");  // B(mt+1) ready
    } else {
      asm volatile("s_waitcnt vmcnt(0)" ::: "memory");   // tail drain
    }
    __builtin_amdgcn_sched_barrier(0);
    COMPUTE_TILE(bfrB);                      // tile mt+1; A(mt+2) lands under
    if (mt + 3 < MT_PER) {
      LOADB(bfrB, bpB0, bpB1);               // issue tile mt+3
      bpB0 += 2 * TSTRIDE; bpB1 += 2 * TSTRIDE;
      asm volatile("s_waitcnt vmcnt(12)" ::: "memory");  // A(mt+2) ready
      __builtin_amdgcn_sched_barrier(0);
    }
  }
#undef LOADB
#undef COMPUTE_TILE

#pragma unroll
  for (int i = 0; i < 16; ++i) {
    float v = rmax[i];
    v = fmaxf(v, __shfl_xor(v, 1));
    v = fmaxf(v, __shfl_xor(v, 2));
    v = fmaxf(v, __shfl_xor(v, 4));
    v = fmaxf(v, __shfl_xor(v, 8));
    rmax[i] = v;
  }
  if (l16 == 0) {
#pragma unroll
    for (int rt = 0; rt < 4; ++rt)
#pragma unroll
      for (int r = 0; r < 4; ++r)
        smax[wc][wr * 64 + rt * 16 + quad * 4 + r] = rmax[rt * 4 + r];
  }
  __syncthreads();
  if (tid < 128) {
    const float v = fmaxf(smax[0][tid], smax[1][tid]);
    pmax[(size_t)(qrow0 + tid) * NCHUNK + ychunk] = v;
  }
}

// ------- Kernel C: reduce partials; uniform row OR exact fp32 re-check -----
__global__ __launch_bounds__(256) void decide_kernel(
    const float* __restrict__ pmax, const float* __restrict__ qe,
    const float* __restrict__ me, const float* __restrict__ labels,
    float* __restrict__ out) {
  const int q = blockIdx.x;
  const int t = threadIdx.x;  // 256
  __shared__ float smx;
  if (t < 64) {
    float v = pmax[(size_t)q * NCHUNK + t];  // NCHUNK == 64
#pragma unroll
    for (int m = 1; m < 64; m <<= 1) v = fmaxf(v, __shfl_xor(v, m));
    if (t == 0) smx = v;
  }
  __syncthreads();
  if (smx <= 0.5f) {  // uniform fast path (expected for all queries)
    if (t < CN) out[(size_t)q * CN + t] = 1.0f / 128.0f;
    return;
  }
  // exact fp32 path (rare / borderline queries only)
  __shared__ float sred[256];
  __shared__ int sidx[256];
  __shared__ float wsum[4];
  const float* qr = qe + (size_t)q * DN;
  float ss = 0.f;
  for (int i = t; i < DN; i += 256) ss += qr[i] * qr[i];
#pragma unroll
  for (int m = 1; m < 64; m <<= 1) ss += __shfl_xor(ss, m);
  if ((t & 63) == 0) wsum[t >> 6] = ss;
  __syncthreads();
  const float qnorm = fmaxf(sqrtf(wsum[0] + wsum[1] + wsum[2] + wsum[3]), 1e-8f);

  float best = -3.0e38f;
  int bidx = 0x7fffffff;
  for (int j = t; j < MN; j += 256) {
    const float* mr = me + (size_t)j * DN;
    float dot = 0.f, ms = 0.f;
    for (int k = 0; k < DN; ++k) {
      float a = qr[k], b = mr[k];
      dot += a * b;
      ms += b * b;
    }
    const float sim = dot / (qnorm * fmaxf(sqrtf(ms), 1e-8f));
    if (sim > best) { best = sim; bidx = j; }  // strict > keeps first index
  }
  sred[t] = best;
  sidx[t] = bidx;
  __syncthreads();
  for (int s = 128; s > 0; s >>= 1) {
    if (t < s) {
      const float ov = sred[t + s];
      const int oi = sidx[t + s];
      if (ov > sred[t] || (ov == sred[t] && oi < sidx[t])) {
        sred[t] = ov;
        sidx[t] = oi;
      }
    }
    __syncthreads();
  }
  const float mx = sred[0];
  const int mi = sidx[0];
  if (t < CN)
    out[(size_t)q * CN + t] =
        (mx > 0.7f) ? labels[(size_t)mi * CN + t] : (1.0f / 128.0f);
}

extern "C" void kernel_launch(void* const* d_in, const int* in_sizes, int n_in,
                              void* d_out, int out_size, void* d_ws,
                              size_t ws_size, hipStream_t stream) {
  const float* qe = (const float*)d_in[0];  // [4096,384] f32
  const float* me = (const float*)d_in[1];  // [65536,384] f32
  const float* lb = (const float*)d_in[2];  // [65536,128] f32
  float* out = (float*)d_out;               // [4096,128] f32

  char* ws = (char*)d_ws;
  const size_t OFF_QN = 0;
  const size_t OFF_MN = OFF_QN + (size_t)QN * DN;        // 1,572,864
  const size_t OFF_PMAX = OFF_MN + (size_t)MN * DN;      // +25,165,824
  unsigned char* qn8 = (unsigned char*)(ws + OFF_QN);
  unsigned char* mn8 = (unsigned char*)(ws + OFF_MN);    // fragment-major
  float* pmax = (float*)(ws + OFF_PMAX);                 // [4096][64] = 1 MB

  nrm_kernel<<<(QN + MN) / 4, 256, 0, stream>>>(qe, me, qn8, mn8);
  gemm_max_kernel<<<dim3(QN / 128, NCHUNK), 256, 0, stream>>>(qn8, mn8, pmax);
  decide_kernel<<<QN, 256, 0, stream>>>(pmax, qe, me, lb, out);
}

// Round 13
// 246.346 us; speedup vs baseline: 2.4173x; 2.4173x over previous
//
#include <hip/hip_runtime.h>
#include <math.h>

// Problem constants
#define QN 4096
#define MN 65536
#define DN 384
#define CN 128
#define NCHUNK 64                 // m-chunks
#define MROWS_PER_CHUNK (MN / NCHUNK)   // 1024
#define MT_PER (MROWS_PER_CHUNK / 64)   // 16 m-tiles (64 rows) per block
#define FRAG_B 2048                     // one fragment-major block: 64 lanes x 32B
#define GSTRIDE (3 * FRAG_B)            // bytes per 16-row group (3 kc)
#define TSTRIDE (4 * GSTRIDE)           // bytes per 64-row tile = 24576

typedef __attribute__((ext_vector_type(8))) int i32x8;
typedef __attribute__((ext_vector_type(4))) int i32x4;
typedef __attribute__((ext_vector_type(4))) float f32x4;

__device__ __forceinline__ void async16(const void* g, void* l) {
  __builtin_amdgcn_global_load_lds(
      (const __attribute__((address_space(1))) unsigned int*)g,
      (__attribute__((address_space(3))) unsigned int*)l, 16, 0, 0);
}

// ------- Kernel A: L2-normalize rows (q then m) -> fp8 --------------------
// q-rows: linear layout (consumed by the GEMM's LDS A-stage).
// m-rows: FRAGMENT-MAJOR layout — the exact per-lane register image of the
// MFMA B-operand (R11, verified: GEMM conflicts 7.08M -> 786K = A-stage only).
__global__ __launch_bounds__(256) void nrm_kernel(const float* __restrict__ qe,
                                                  const float* __restrict__ me,
                                                  unsigned char* __restrict__ yq,
                                                  unsigned char* __restrict__ ym) {
  const int row = blockIdx.x * 4 + (threadIdx.x >> 6);
  const int lane = threadIdx.x & 63;
  const float* xr = (row < QN) ? qe + (size_t)row * DN
                               : me + (size_t)(row - QN) * DN;
  float2 v[3];
  float ss = 0.f;
#pragma unroll
  for (int i = 0; i < 3; ++i) {
    v[i] = *(const float2*)&xr[lane * 2 + i * 128];
    ss += v[i].x * v[i].x + v[i].y * v[i].y;
  }
#pragma unroll
  for (int m = 1; m < 64; m <<= 1) ss += __shfl_xor(ss, m);
  const float scale = 1.0f / fmaxf(sqrtf(ss), 1e-8f);
  if (row < QN) {
    unsigned short* yw = (unsigned short*)(yq + (size_t)row * DN);
#pragma unroll
    for (int i = 0; i < 3; ++i) {
      const int p = __builtin_amdgcn_cvt_pk_fp8_f32(v[i].x * scale,
                                                    v[i].y * scale, 0, false);
      yw[lane + i * 64] = (unsigned short)(p & 0xffff);
    }
  } else {
    const int mr = row - QN;
    const int g = mr >> 4, r15 = mr & 15;
    const int fl = ((lane >> 4) << 4) + r15;   // fragment lane index
    unsigned short* yw = (unsigned short*)ym;
#pragma unroll
    for (int i = 0; i < 3; ++i) {
      const int p = __builtin_amdgcn_cvt_pk_fp8_f32(v[i].x * scale,
                                                    v[i].y * scale, 0, false);
      yw[((size_t)(g * 3 + i) * 64 + fl) * 16 + (lane & 15)] =
          (unsigned short)(p & 0xffff);
    }
  }
}

// ------- Kernel B: MX-fp8 GEMM, barrier-free + ct-split prefetch -----------
// R13: R12's full dual-tile register dbuf spilled (combined VGPR+AGPR budget
// = 256/wave at 2 waves/SIMD; R11 sits ~220, +48 broke it). Same overlap,
// zero extra live state: split each tile into ct-halves pre[3] (ct0) and
// b1[3] (ct1) — 48 B-state VGPRs, exactly R11's bfr footprint — and issue
// each half one MFMA-cluster (~415 cyc) before its consumption:
//   iter mt: issue ct1(mt) | MFMA cluster A on pre=ct0(mt) (no wait) |
//            issue ct0(mt+1)->pre | MFMA cluster B on b1 (covered by A).
// Targets R11's measured 745-cyc per-visit load-wait (MfmaUtil 54%).
// Backend inserts exact dep waits; sched_barrier(0) pins issue-before-MFMA.
__global__ __launch_bounds__(256, 2) void gemm_max_kernel(
    const unsigned char* __restrict__ qn8, const unsigned char* __restrict__ mn8,
    float* __restrict__ pmax) {
  __shared__ unsigned char As[128 * DN];   // 48 KB: A staging only
  __shared__ float smax[2][128];

  const int tid = threadIdx.x;
  const int wave = tid >> 6, lane = tid & 63;
  const int wr = wave >> 1, wc = wave & 1;   // waves: 2x2 over 128q x 64m
  const int quad = lane >> 4, l16 = lane & 15;
  const int r7 = l16 & 7;

  // --- XCD-partitioned bijective swizzle (HW assigns XCD = linear id % 8) ---
  const int bid = blockIdx.y * gridDim.x + blockIdx.x;  // linear dispatch id
  const int xcd = bid & 7;
  const int j = bid >> 3;                    // 0..255 within this XCD
  const int ychunk = (xcd << 3) | (j >> 5);  // 8 m-chunks per XCD
  const int qrow0 = (j & 31) * 128;          // x sweeps fastest
  const int mchunk0 = ychunk * MROWS_PER_CHUNK;

  float rmax[16];
#pragma unroll
  for (int i = 0; i < 16; ++i) rmax[i] = -3.0e38f;

  // ---- stage A tile (128x384 = 48 KB) once, hoist fragments to registers --
  {
    const unsigned char* abase = qn8 + (size_t)qrow0 * DN;
#pragma unroll
    for (int i = 0; i < 12; ++i) {
      const int ci = i * 256 + tid;               // 16B chunk 0..3071
      const int row = ci / 24;
      const int jj = ci - row * 24;
      const int gj = (jj & 24) | ((jj ^ row) & 7);  // XOR-swizzled source chunk
      async16(abase + row * DN + gj * 16, &As[(i * 256 + wave * 64) * 16]);
    }
  }
  __syncthreads();  // full drain: A staged
  i32x8 afr[3][4];
#pragma unroll
  for (int kc = 0; kc < 3; ++kc)
#pragma unroll
    for (int rt = 0; rt < 4; ++rt) {
      const unsigned char* p = &As[(wr * 64 + rt * 16 + l16) * DN];
      i32x4 lo = *(const i32x4*)&p[(kc * 8 + ((quad * 2 + 0) ^ r7)) * 16];
      i32x4 hi = *(const i32x4*)&p[(kc * 8 + ((quad * 2 + 1) ^ r7)) * 16];
      afr[kc][rt][0] = lo[0]; afr[kc][rt][1] = lo[1];
      afr[kc][rt][2] = lo[2]; afr[kc][rt][3] = lo[3];
      afr[kc][rt][4] = hi[0]; afr[kc][rt][5] = hi[1];
      afr[kc][rt][6] = hi[2]; afr[kc][rt][7] = hi[3];
    }
  // no further LDS use until epilogue; NO barriers in the main loop

  // --- per-wave fragment-major B pointers (ct=0 -> group g0, ct=1 -> g0+1) -
  const int g0 = (mchunk0 >> 4) + wc * 2;
  const unsigned char* bp0 = mn8 + ((size_t)g0 * 3 * 64 + lane) * 32;  // ct0
  const unsigned char* bp1 = bp0 + GSTRIDE;                            // ct1

  i32x8 pre[3], b1[3];
  // prologue: load ct0 of tile 0 into pre; bp0 then runs one tile ahead
#pragma unroll
  for (int kc = 0; kc < 3; ++kc)
    pre[kc] = *(const i32x8*)(bp0 + kc * FRAG_B);
  bp0 += TSTRIDE;

#pragma unroll 1
  for (int mt = 0; mt < MT_PER; ++mt) {
    // issue ct1(mt) loads (consumed in cluster B, after ~415 cyc of cluster A)
#pragma unroll
    for (int kc = 0; kc < 3; ++kc)
      b1[kc] = *(const i32x8*)(bp1 + kc * FRAG_B);
    bp1 += TSTRIDE;
    __builtin_amdgcn_sched_barrier(0);   // keep load issue above cluster A

    // ---- cluster A: ct0 MFMAs on pre (loaded one cluster ago; no wait) ----
    {
      f32x4 acc[4];
#pragma unroll
      for (int rt = 0; rt < 4; ++rt) acc[rt] = (f32x4){0.f, 0.f, 0.f, 0.f};
      __builtin_amdgcn_s_setprio(1);
#pragma unroll
      for (int kc = 0; kc < 3; ++kc)
#pragma unroll
        for (int rt = 0; rt < 4; ++rt)
          acc[rt] = __builtin_amdgcn_mfma_scale_f32_16x16x128_f8f6f4(
              afr[kc][rt], pre[kc], acc[rt], 0, 0, 0, 0x7f7f7f7f, 0,
              0x7f7f7f7f);
      __builtin_amdgcn_s_setprio(0);
#pragma unroll
      for (int rt = 0; rt < 4; ++rt)
#pragma unroll
        for (int r = 0; r < 4; ++r)
          rmax[rt * 4 + r] = fmaxf(rmax[rt * 4 + r], acc[rt][r]);
    }
    __builtin_amdgcn_sched_barrier(0);   // cluster A stays above pre reload

    // issue ct0(mt+1) into pre (consumed next iter's cluster A; covered by B)
    if (mt + 1 < MT_PER) {
#pragma unroll
      for (int kc = 0; kc < 3; ++kc)
        pre[kc] = *(const i32x8*)(bp0 + kc * FRAG_B);
      bp0 += TSTRIDE;
    }
    __builtin_amdgcn_sched_barrier(0);   // keep pre issue above cluster B

    // ---- cluster B: ct1 MFMAs on b1 (backend waits only on b1 deps) -------
    {
      f32x4 acc[4];
#pragma unroll
      for (int rt = 0; rt < 4; ++rt) acc[rt] = (f32x4){0.f, 0.f, 0.f, 0.f};
      __builtin_amdgcn_s_setprio(1);
#pragma unroll
      for (int kc = 0; kc < 3; ++kc)
#pragma unroll
        for (int rt = 0; rt < 4; ++rt)
          acc[rt] = __builtin_amdgcn_mfma_scale_f32_16x16x128_f8f6f4(
              afr[kc][rt], b1[kc], acc[rt], 0, 0, 0, 0x7f7f7f7f, 0,
              0x7f7f7f7f);
      __builtin_amdgcn_s_setprio(0);
#pragma unroll
      for (int rt = 0; rt < 4; ++rt)
#pragma unroll
        for (int r = 0; r < 4; ++r)
          rmax[rt * 4 + r] = fmaxf(rmax[rt * 4 + r], acc[rt][r]);
    }
  }

#pragma unroll
  for (int i = 0; i < 16; ++i) {
    float v = rmax[i];
    v = fmaxf(v, __shfl_xor(v, 1));
    v = fmaxf(v, __shfl_xor(v, 2));
    v = fmaxf(v, __shfl_xor(v, 4));
    v = fmaxf(v, __shfl_xor(v, 8));
    rmax[i] = v;
  }
  if (l16 == 0) {
#pragma unroll
    for (int rt = 0; rt < 4; ++rt)
#pragma unroll
      for (int r = 0; r < 4; ++r)
        smax[wc][wr * 64 + rt * 16 + quad * 4 + r] = rmax[rt * 4 + r];
  }
  __syncthreads();
  if (tid < 128) {
    const float v = fmaxf(smax[0][tid], smax[1][tid]);
    pmax[(size_t)(qrow0 + tid) * NCHUNK + ychunk] = v;
  }
}

// ------- Kernel C: reduce partials; uniform row OR exact fp32 re-check -----
__global__ __launch_bounds__(256) void decide_kernel(
    const float* __restrict__ pmax, const float* __restrict__ qe,
    const float* __restrict__ me, const float* __restrict__ labels,
    float* __restrict__ out) {
  const int q = blockIdx.x;
  const int t = threadIdx.x;  // 256
  __shared__ float smx;
  if (t < 64) {
    float v = pmax[(size_t)q * NCHUNK + t];  // NCHUNK == 64
#pragma unroll
    for (int m = 1; m < 64; m <<= 1) v = fmaxf(v, __shfl_xor(v, m));
    if (t == 0) smx = v;
  }
  __syncthreads();
  if (smx <= 0.5f) {  // uniform fast path (expected for all queries)
    if (t < CN) out[(size_t)q * CN + t] = 1.0f / 128.0f;
    return;
  }
  // exact fp32 path (rare / borderline queries only)
  __shared__ float sred[256];
  __shared__ int sidx[256];
  __shared__ float wsum[4];
  const float* qr = qe + (size_t)q * DN;
  float ss = 0.f;
  for (int i = t; i < DN; i += 256) ss += qr[i] * qr[i];
#pragma unroll
  for (int m = 1; m < 64; m <<= 1) ss += __shfl_xor(ss, m);
  if ((t & 63) == 0) wsum[t >> 6] = ss;
  __syncthreads();
  const float qnorm = fmaxf(sqrtf(wsum[0] + wsum[1] + wsum[2] + wsum[3]), 1e-8f);

  float best = -3.0e38f;
  int bidx = 0x7fffffff;
  for (int j = t; j < MN; j += 256) {
    const float* mr = me + (size_t)j * DN;
    float dot = 0.f, ms = 0.f;
    for (int k = 0; k < DN; ++k) {
      float a = qr[k], b = mr[k];
      dot += a * b;
      ms += b * b;
    }
    const float sim = dot / (qnorm * fmaxf(sqrtf(ms), 1e-8f));
    if (sim > best) { best = sim; bidx = j; }  // strict > keeps first index
  }
  sred[t] = best;
  sidx[t] = bidx;
  __syncthreads();
  for (int s = 128; s > 0; s >>= 1) {
    if (t < s) {
      const float ov = sred[t + s];
      const int oi = sidx[t + s];
      if (ov > sred[t] || (ov == sred[t] && oi < sidx[t])) {
        sred[t] = ov;
        sidx[t] = oi;
      }
    }
    __syncthreads();
  }
  const float mx = sred[0];
  const int mi = sidx[0];
  if (t < CN)
    out[(size_t)q * CN + t] =
        (mx > 0.7f) ? labels[(size_t)mi * CN + t] : (1.0f / 128.0f);
}

extern "C" void kernel_launch(void* const* d_in, const int* in_sizes, int n_in,
                              void* d_out, int out_size, void* d_ws,
                              size_t ws_size, hipStream_t stream) {
  const float* qe = (const float*)d_in[0];  // [4096,384] f32
  const float* me = (const float*)d_in[1];  // [65536,384] f32
  const float* lb = (const float*)d_in[2];  // [65536,128] f32
  float* out = (float*)d_out;               // [4096,128] f32

  char* ws = (char*)d_ws;
  const size_t OFF_QN = 0;
  const size_t OFF_MN = OFF_QN + (size_t)QN * DN;        // 1,572,864
  const size_t OFF_PMAX = OFF_MN + (size_t)MN * DN;      // +25,165,824
  unsigned char* qn8 = (unsigned char*)(ws + OFF_QN);
  unsigned char* mn8 = (unsigned char*)(ws + OFF_MN);    // fragment-major
  float* pmax = (float*)(ws + OFF_PMAX);                 // [4096][64] = 1 MB

  nrm_kernel<<<(QN + MN) / 4, 256, 0, stream>>>(qe, me, qn8, mn8);
  gemm_max_kernel<<<dim3(QN / 128, NCHUNK), 256, 0, stream>>>(qn8, mn8, pmax);
  decide_kernel<<<QN, 256, 0, stream>>>(pmax, qe, me, lb, out);
}

// Round 14
// 229.853 us; speedup vs baseline: 2.5908x; 1.0718x over previous
//
#include <hip/hip_runtime.h>
#include <math.h>

// Problem constants
#define QN 4096
#define MN 65536
#define DN 384
#define CN 128
#define NCHUNK 64                 // m-chunks
#define MROWS_PER_CHUNK (MN / NCHUNK)   // 1024
#define MT_PER (MROWS_PER_CHUNK / 64)   // 16 m-tiles (64 rows) per block
// fp4 fragment-major B: one fragment block = 64 lanes x 16B = 1024 B
#define FRAG_B 1024
#define GSTRIDE (3 * FRAG_B)            // bytes per 16-row group (3 kc) = 3072
#define TSTRIDE (4 * GSTRIDE)           // bytes per 64-row tile = 12288

typedef __attribute__((ext_vector_type(8))) int i32x8;
typedef __attribute__((ext_vector_type(4))) int i32x4;
typedef __attribute__((ext_vector_type(4))) float f32x4;

__device__ __forceinline__ void async16(const void* g, void* l) {
  __builtin_amdgcn_global_load_lds(
      (const __attribute__((address_space(1))) unsigned int*)g,
      (__attribute__((address_space(3))) unsigned int*)l, 16, 0, 0);
}

// e2m1 fp4 encode (nearest): levels 0,0.5,1,1.5,2,3,4,6; bit3 = sign.
__device__ __forceinline__ unsigned fp4e(float x) {
  const float a = fabsf(x);
  unsigned c = (unsigned)(a >= 0.25f) + (a >= 0.75f) + (a >= 1.25f) +
               (a >= 1.75f) + (a >= 2.5f) + (a >= 3.5f) + (a >= 5.0f);
  return ((x < 0.f) ? 8u : 0u) | c;
}

// ------- Kernel A: L2-normalize rows; q -> fp8 linear, m -> fp4 frag-major -
// m-rows: B stored as e2m1 fp4, value x16 (MFMA B-scale 2^-4 undoes it), in
// the fragment-major register image of the f8f6f4 B-operand (blgp=4): lane
// fl = quad*16 + (mr&15) holds 16B = K-bytes [quad*32..+32) as nibbles,
// k-even in low nibble (OCP order). Halves the GEMM's L1 bytes — R13 showed
// the GEMM sits exactly at the 64 B/cyc/CU vector-return ceiling.
__global__ __launch_bounds__(256) void nrm_kernel(const float* __restrict__ qe,
                                                  const float* __restrict__ me,
                                                  unsigned char* __restrict__ yq,
                                                  unsigned char* __restrict__ ym) {
  const int row = blockIdx.x * 4 + (threadIdx.x >> 6);
  const int lane = threadIdx.x & 63;
  const float* xr = (row < QN) ? qe + (size_t)row * DN
                               : me + (size_t)(row - QN) * DN;
  float2 v[3];
  float ss = 0.f;
#pragma unroll
  for (int i = 0; i < 3; ++i) {
    v[i] = *(const float2*)&xr[lane * 2 + i * 128];
    ss += v[i].x * v[i].x + v[i].y * v[i].y;
  }
#pragma unroll
  for (int m = 1; m < 64; m <<= 1) ss += __shfl_xor(ss, m);
  const float scale = 1.0f / fmaxf(sqrtf(ss), 1e-8f);
  if (row < QN) {
    unsigned short* yw = (unsigned short*)(yq + (size_t)row * DN);
#pragma unroll
    for (int i = 0; i < 3; ++i) {
      const int p = __builtin_amdgcn_cvt_pk_fp8_f32(v[i].x * scale,
                                                    v[i].y * scale, 0, false);
      yw[lane + i * 64] = (unsigned short)(p & 0xffff);
    }
  } else {
    const int mr = row - QN;
    const int g = mr >> 4, r15 = mr & 15;
    const int fl = ((lane >> 4) << 4) + r15;   // fragment lane index
    const float s16 = scale * 16.0f;
#pragma unroll
    for (int i = 0; i < 3; ++i) {
      const unsigned b = fp4e(v[i].x * s16) | (fp4e(v[i].y * s16) << 4);
      ym[((size_t)(g * 3 + i) * 64 + fl) * 16 + (lane & 15)] =
          (unsigned char)b;
    }
  }
}

// ------- Kernel B: MX fp8xfp4 GEMM, barrier-free + ct-split prefetch -------
// R14: R13 verbatim except B is fp4 (blgp=4, B-scale 2^-4): B loads are 16B
// per fragment (one dwordx4) — halves L1 traffic from the measured 64 B/cyc
// ceiling to 32, making the MFMA pipe (830 cyc/visit) the binding constraint.
// B-state stays in i32x8 shells (zero-init once; loads fill low 4 regs; the
// HW reads only v[0:3] for fp4) -> zero per-iter movs, VGPR unchanged.
__global__ __launch_bounds__(256, 2) void gemm_max_kernel(
    const unsigned char* __restrict__ qn8, const unsigned char* __restrict__ mn4,
    float* __restrict__ pmax) {
  __shared__ unsigned char As[128 * DN];   // 48 KB: A staging only
  __shared__ float smax[2][128];

  const int tid = threadIdx.x;
  const int wave = tid >> 6, lane = tid & 63;
  const int wr = wave >> 1, wc = wave & 1;   // waves: 2x2 over 128q x 64m
  const int quad = lane >> 4, l16 = lane & 15;
  const int r7 = l16 & 7;

  // --- XCD-partitioned bijective swizzle (HW assigns XCD = linear id % 8) ---
  const int bid = blockIdx.y * gridDim.x + blockIdx.x;  // linear dispatch id
  const int xcd = bid & 7;
  const int j = bid >> 3;                    // 0..255 within this XCD
  const int ychunk = (xcd << 3) | (j >> 5);  // 8 m-chunks per XCD
  const int qrow0 = (j & 31) * 128;          // x sweeps fastest
  const int mchunk0 = ychunk * MROWS_PER_CHUNK;

  float rmax[16];
#pragma unroll
  for (int i = 0; i < 16; ++i) rmax[i] = -3.0e38f;

  // ---- stage A tile (128x384 = 48 KB) once, hoist fragments to registers --
  {
    const unsigned char* abase = qn8 + (size_t)qrow0 * DN;
#pragma unroll
    for (int i = 0; i < 12; ++i) {
      const int ci = i * 256 + tid;               // 16B chunk 0..3071
      const int row = ci / 24;
      const int jj = ci - row * 24;
      const int gj = (jj & 24) | ((jj ^ row) & 7);  // XOR-swizzled source chunk
      async16(abase + row * DN + gj * 16, &As[(i * 256 + wave * 64) * 16]);
    }
  }
  __syncthreads();  // full drain: A staged
  i32x8 afr[3][4];
#pragma unroll
  for (int kc = 0; kc < 3; ++kc)
#pragma unroll
    for (int rt = 0; rt < 4; ++rt) {
      const unsigned char* p = &As[(wr * 64 + rt * 16 + l16) * DN];
      i32x4 lo = *(const i32x4*)&p[(kc * 8 + ((quad * 2 + 0) ^ r7)) * 16];
      i32x4 hi = *(const i32x4*)&p[(kc * 8 + ((quad * 2 + 1) ^ r7)) * 16];
      afr[kc][rt][0] = lo[0]; afr[kc][rt][1] = lo[1];
      afr[kc][rt][2] = lo[2]; afr[kc][rt][3] = lo[3];
      afr[kc][rt][4] = hi[0]; afr[kc][rt][5] = hi[1];
      afr[kc][rt][6] = hi[2]; afr[kc][rt][7] = hi[3];
    }
  // no further LDS use until epilogue; NO barriers in the main loop

  // --- per-wave fragment-major fp4 B pointers (ct0 -> g0, ct1 -> g0+1) -----
  const int g0 = (mchunk0 >> 4) + wc * 2;
  const unsigned char* bp0 = mn4 + ((size_t)g0 * 3 * 64 + lane) * 16;  // ct0
  const unsigned char* bp1 = bp0 + GSTRIDE;                            // ct1

  i32x8 pre[3], b1[3];
#pragma unroll
  for (int kc = 0; kc < 3; ++kc) {
    pre[kc] = (i32x8){0, 0, 0, 0, 0, 0, 0, 0};
    b1[kc] = (i32x8){0, 0, 0, 0, 0, 0, 0, 0};
  }
  // prologue: load ct0 of tile 0 into pre (low 4 regs); bp0 runs a tile ahead
#pragma unroll
  for (int kc = 0; kc < 3; ++kc) {
    i32x4 t = *(const i32x4*)(bp0 + kc * FRAG_B);
    pre[kc][0] = t[0]; pre[kc][1] = t[1]; pre[kc][2] = t[2]; pre[kc][3] = t[3];
  }
  bp0 += TSTRIDE;

#pragma unroll 1
  for (int mt = 0; mt < MT_PER; ++mt) {
    // issue ct1(mt) loads (consumed in cluster B, covered by cluster A)
#pragma unroll
    for (int kc = 0; kc < 3; ++kc) {
      i32x4 t = *(const i32x4*)(bp1 + kc * FRAG_B);
      b1[kc][0] = t[0]; b1[kc][1] = t[1]; b1[kc][2] = t[2]; b1[kc][3] = t[3];
    }
    bp1 += TSTRIDE;
    __builtin_amdgcn_sched_barrier(0);   // keep load issue above cluster A

    // ---- cluster A: ct0 MFMAs on pre (loaded one cluster ago; no wait) ----
    {
      f32x4 acc[4];
#pragma unroll
      for (int rt = 0; rt < 4; ++rt) acc[rt] = (f32x4){0.f, 0.f, 0.f, 0.f};
      __builtin_amdgcn_s_setprio(1);
#pragma unroll
      for (int kc = 0; kc < 3; ++kc)
#pragma unroll
        for (int rt = 0; rt < 4; ++rt)
          acc[rt] = __builtin_amdgcn_mfma_scale_f32_16x16x128_f8f6f4(
              afr[kc][rt], pre[kc], acc[rt], 0, 4,  // A fp8, B fp4
              0, 0x7f7f7f7f, 0, 0x7b7b7b7b);        // B-scale 2^-4
      __builtin_amdgcn_s_setprio(0);
#pragma unroll
      for (int rt = 0; rt < 4; ++rt)
#pragma unroll
        for (int r = 0; r < 4; ++r)
          rmax[rt * 4 + r] = fmaxf(rmax[rt * 4 + r], acc[rt][r]);
    }
    __builtin_amdgcn_sched_barrier(0);   // cluster A stays above pre reload

    // issue ct0(mt+1) into pre (consumed next iter's cluster A)
    if (mt + 1 < MT_PER) {
#pragma unroll
      for (int kc = 0; kc < 3; ++kc) {
        i32x4 t = *(const i32x4*)(bp0 + kc * FRAG_B);
        pre[kc][0] = t[0]; pre[kc][1] = t[1];
        pre[kc][2] = t[2]; pre[kc][3] = t[3];
      }
      bp0 += TSTRIDE;
    }
    __builtin_amdgcn_sched_barrier(0);   // keep pre issue above cluster B

    // ---- cluster B: ct1 MFMAs on b1 -----------------------------------
    {
      f32x4 acc[4];
#pragma unroll
      for (int rt = 0; rt < 4; ++rt) acc[rt] = (f32x4){0.f, 0.f, 0.f, 0.f};
      __builtin_amdgcn_s_setprio(1);
#pragma unroll
      for (int kc = 0; kc < 3; ++kc)
#pragma unroll
        for (int rt = 0; rt < 4; ++rt)
          acc[rt] = __builtin_amdgcn_mfma_scale_f32_16x16x128_f8f6f4(
              afr[kc][rt], b1[kc], acc[rt], 0, 4,   // A fp8, B fp4
              0, 0x7f7f7f7f, 0, 0x7b7b7b7b);        // B-scale 2^-4
      __builtin_amdgcn_s_setprio(0);
#pragma unroll
      for (int rt = 0; rt < 4; ++rt)
#pragma unroll
        for (int r = 0; r < 4; ++r)
          rmax[rt * 4 + r] = fmaxf(rmax[rt * 4 + r], acc[rt][r]);
    }
  }

#pragma unroll
  for (int i = 0; i < 16; ++i) {
    float v = rmax[i];
    v = fmaxf(v, __shfl_xor(v, 1));
    v = fmaxf(v, __shfl_xor(v, 2));
    v = fmaxf(v, __shfl_xor(v, 4));
    v = fmaxf(v, __shfl_xor(v, 8));
    rmax[i] = v;
  }
  if (l16 == 0) {
#pragma unroll
    for (int rt = 0; rt < 4; ++rt)
#pragma unroll
      for (int r = 0; r < 4; ++r)
        smax[wc][wr * 64 + rt * 16 + quad * 4 + r] = rmax[rt * 4 + r];
  }
  __syncthreads();
  if (tid < 128) {
    const float v = fmaxf(smax[0][tid], smax[1][tid]);
    pmax[(size_t)(qrow0 + tid) * NCHUNK + ychunk] = v;
  }
}

// ------- Kernel C: reduce partials; uniform row OR exact fp32 re-check -----
__global__ __launch_bounds__(256) void decide_kernel(
    const float* __restrict__ pmax, const float* __restrict__ qe,
    const float* __restrict__ me, const float* __restrict__ labels,
    float* __restrict__ out) {
  const int q = blockIdx.x;
  const int t = threadIdx.x;  // 256
  __shared__ float smx;
  if (t < 64) {
    float v = pmax[(size_t)q * NCHUNK + t];  // NCHUNK == 64
#pragma unroll
    for (int m = 1; m < 64; m <<= 1) v = fmaxf(v, __shfl_xor(v, m));
    if (t == 0) smx = v;
  }
  __syncthreads();
  if (smx <= 0.5f) {  // uniform fast path (expected for all queries)
    if (t < CN) out[(size_t)q * CN + t] = 1.0f / 128.0f;
    return;
  }
  // exact fp32 path (rare / borderline queries only)
  __shared__ float sred[256];
  __shared__ int sidx[256];
  __shared__ float wsum[4];
  const float* qr = qe + (size_t)q * DN;
  float ss = 0.f;
  for (int i = t; i < DN; i += 256) ss += qr[i] * qr[i];
#pragma unroll
  for (int m = 1; m < 64; m <<= 1) ss += __shfl_xor(ss, m);
  if ((t & 63) == 0) wsum[t >> 6] = ss;
  __syncthreads();
  const float qnorm = fmaxf(sqrtf(wsum[0] + wsum[1] + wsum[2] + wsum[3]), 1e-8f);

  float best = -3.0e38f;
  int bidx = 0x7fffffff;
  for (int j = t; j < MN; j += 256) {
    const float* mr = me + (size_t)j * DN;
    float dot = 0.f, ms = 0.f;
    for (int k = 0; k < DN; ++k) {
      float a = qr[k], b = mr[k];
      dot += a * b;
      ms += b * b;
    }
    const float sim = dot / (qnorm * fmaxf(sqrtf(ms), 1e-8f));
    if (sim > best) { best = sim; bidx = j; }  // strict > keeps first index
  }
  sred[t] = best;
  sidx[t] = bidx;
  __syncthreads();
  for (int s = 128; s > 0; s >>= 1) {
    if (t < s) {
      const float ov = sred[t + s];
      const int oi = sidx[t + s];
      if (ov > sred[t] || (ov == sred[t] && oi < sidx[t])) {
        sred[t] = ov;
        sidx[t] = oi;
      }
    }
    __syncthreads();
  }
  const float mx = sred[0];
  const int mi = sidx[0];
  if (t < CN)
    out[(size_t)q * CN + t] =
        (mx > 0.7f) ? labels[(size_t)mi * CN + t] : (1.0f / 128.0f);
}

extern "C" void kernel_launch(void* const* d_in, const int* in_sizes, int n_in,
                              void* d_out, int out_size, void* d_ws,
                              size_t ws_size, hipStream_t stream) {
  const float* qe = (const float*)d_in[0];  // [4096,384] f32
  const float* me = (const float*)d_in[1];  // [65536,384] f32
  const float* lb = (const float*)d_in[2];  // [65536,128] f32
  float* out = (float*)d_out;               // [4096,128] f32

  char* ws = (char*)d_ws;
  const size_t OFF_QN = 0;
  const size_t OFF_MN = OFF_QN + (size_t)QN * DN;        // 1,572,864
  const size_t OFF_PMAX = OFF_MN + (size_t)MN * DN;      // +25,165,824 (keep)
  unsigned char* qn8 = (unsigned char*)(ws + OFF_QN);
  unsigned char* mn4 = (unsigned char*)(ws + OFF_MN);    // fp4 fragment-major
  float* pmax = (float*)(ws + OFF_PMAX);                 // [4096][64] = 1 MB

  nrm_kernel<<<(QN + MN) / 4, 256, 0, stream>>>(qe, me, qn8, mn4);
  gemm_max_kernel<<<dim3(QN / 128, NCHUNK), 256, 0, stream>>>(qn8, mn4, pmax);
  decide_kernel<<<QN, 256, 0, stream>>>(pmax, qe, me, lb, out);
}

// Round 15
// 212.687 us; speedup vs baseline: 2.7999x; 1.0807x over previous
//
#include <hip/hip_runtime.h>
#include <math.h>

// Problem constants
#define QN 4096
#define MN 65536
#define DN 384
#define CN 128
#define NCHUNK 64                 // m-chunks
#define MROWS_PER_CHUNK (MN / NCHUNK)   // 1024
#define MT_PER (MROWS_PER_CHUNK / 64)   // 16 m-tiles (64 rows) per block
// fp4 fragment-major: one fragment block = 64 lanes x 16B = 1024 B
#define FRAG_B 1024
#define GSTRIDE (3 * FRAG_B)            // bytes per 16-row group (3 kc) = 3072
#define TSTRIDE (4 * GSTRIDE)           // bytes per 64-row tile = 12288

typedef __attribute__((ext_vector_type(8))) int i32x8;
typedef __attribute__((ext_vector_type(4))) int i32x4;
typedef __attribute__((ext_vector_type(4))) float f32x4;

// e2m1 fp4 encode (nearest): levels 0,0.5,1,1.5,2,3,4,6; bit3 = sign.
__device__ __forceinline__ unsigned fp4e(float x) {
  const float a = fabsf(x);
  unsigned c = (unsigned)(a >= 0.25f) + (a >= 0.75f) + (a >= 1.25f) +
               (a >= 1.75f) + (a >= 2.5f) + (a >= 3.5f) + (a >= 5.0f);
  return ((x < 0.f) ? 8u : 0u) | c;
}

// ------- Kernel A: L2-normalize rows; BOTH q and m -> fp4 fragment-major ---
// Fragment-major = the per-lane register image of the f8f6f4 fp4 operand
// (fmt=4): fragment lane fl = quad*16 + (row&15) holds 16 B = K-bytes
// [quad*32 .. +32) as nibbles, k-even in low nibble. Value x16; the MFMA
// operand scale 2^-4 (0x7b) undoes it. Identical packing verified for B in
// R14 (absmax 0.0); A's lane map (row = l&15, K-slice = (l>>4)*32) is
// structurally the same, so the code is shared.
__global__ __launch_bounds__(256) void nrm_kernel(const float* __restrict__ qe,
                                                  const float* __restrict__ me,
                                                  unsigned char* __restrict__ yq,
                                                  unsigned char* __restrict__ ym) {
  const int row = blockIdx.x * 4 + (threadIdx.x >> 6);
  const int lane = threadIdx.x & 63;
  const int isq = (row < QN);
  const int r = isq ? row : row - QN;
  const float* xr = isq ? qe + (size_t)r * DN : me + (size_t)r * DN;
  unsigned char* yb = isq ? yq : ym;
  float2 v[3];
  float ss = 0.f;
#pragma unroll
  for (int i = 0; i < 3; ++i) {
    v[i] = *(const float2*)&xr[lane * 2 + i * 128];
    ss += v[i].x * v[i].x + v[i].y * v[i].y;
  }
#pragma unroll
  for (int m = 1; m < 64; m <<= 1) ss += __shfl_xor(ss, m);
  const float s16 = (16.0f / fmaxf(sqrtf(ss), 1e-8f));
  const int g = r >> 4;
  const int fl = ((lane >> 4) << 4) + (r & 15);   // fragment lane index
#pragma unroll
  for (int i = 0; i < 3; ++i) {
    const unsigned b = fp4e(v[i].x * s16) | (fp4e(v[i].y * s16) << 4);
    yb[((size_t)(g * 3 + i) * 64 + fl) * 16 + (lane & 15)] = (unsigned char)b;
  }
}

// ------- Kernel B: MX fp4xfp4 GEMM, fully barrier-free, zero staging -------
// R15: both operands fp4 (cbsz=4, blgp=4) -> the f8f6f4 MFMA runs at the fp4
// rate (16x16 ubench 7228 vs 4661 TF = 1.55x; mixed formats run at the wider
// rate — R14's 62% MfmaUtil was the fp8-rate pipe itself). A is now ALSO
// fragment-major in global, so the LDS A-stage is deleted: afr = 12 coalesced
// dwordx4 from L2 at block start, ZERO barriers before the epilogue, LDS = 1KB
// (occupancy no longer LDS-capped). Shell count identical to R14 (18x i32x8)
// -> register pressure unchanged (~88 arch VGPR). ct-split prefetch retained.
__global__ __launch_bounds__(256, 2) void gemm_max_kernel(
    const unsigned char* __restrict__ qn4, const unsigned char* __restrict__ mn4,
    float* __restrict__ pmax) {
  __shared__ float smax[2][128];

  const int tid = threadIdx.x;
  const int wave = tid >> 6, lane = tid & 63;
  const int wr = wave >> 1, wc = wave & 1;   // waves: 2x2 over 128q x 64m
  const int quad = lane >> 4, l16 = lane & 15;

  // --- XCD-partitioned bijective swizzle (HW assigns XCD = linear id % 8) ---
  const int bid = blockIdx.y * gridDim.x + blockIdx.x;  // linear dispatch id
  const int xcd = bid & 7;
  const int j = bid >> 3;                    // 0..255 within this XCD
  const int ychunk = (xcd << 3) | (j >> 5);  // 8 m-chunks per XCD
  const int qrow0 = (j & 31) * 128;          // x sweeps fastest
  const int mchunk0 = ychunk * MROWS_PER_CHUNK;

  float rmax[16];
#pragma unroll
  for (int i = 0; i < 16; ++i) rmax[i] = -3.0e38f;

  // ---- A fragments direct from global (fragment-major, L2-resident) -------
  const int gq0 = (qrow0 >> 4) + wr * 4;     // 16-row group of rt=0
  i32x8 afr[3][4];
#pragma unroll
  for (int kc = 0; kc < 3; ++kc)
#pragma unroll
    for (int rt = 0; rt < 4; ++rt) {
      afr[kc][rt] = (i32x8){0, 0, 0, 0, 0, 0, 0, 0};
      i32x4 t = *(const i32x4*)(qn4 +
          ((size_t)((gq0 + rt) * 3 + kc) * 64 + lane) * 16);
      afr[kc][rt][0] = t[0]; afr[kc][rt][1] = t[1];
      afr[kc][rt][2] = t[2]; afr[kc][rt][3] = t[3];
    }

  // --- per-wave fragment-major fp4 B pointers (ct0 -> g0, ct1 -> g0+1) -----
  const int g0 = (mchunk0 >> 4) + wc * 2;
  const unsigned char* bp0 = mn4 + ((size_t)g0 * 3 * 64 + lane) * 16;  // ct0
  const unsigned char* bp1 = bp0 + GSTRIDE;                            // ct1

  i32x8 pre[3], b1[3];
#pragma unroll
  for (int kc = 0; kc < 3; ++kc) {
    pre[kc] = (i32x8){0, 0, 0, 0, 0, 0, 0, 0};
    b1[kc] = (i32x8){0, 0, 0, 0, 0, 0, 0, 0};
  }
  // prologue: load ct0 of tile 0 into pre; bp0 then runs one tile ahead
#pragma unroll
  for (int kc = 0; kc < 3; ++kc) {
    i32x4 t = *(const i32x4*)(bp0 + kc * FRAG_B);
    pre[kc][0] = t[0]; pre[kc][1] = t[1]; pre[kc][2] = t[2]; pre[kc][3] = t[3];
  }
  bp0 += TSTRIDE;

#pragma unroll 1
  for (int mt = 0; mt < MT_PER; ++mt) {
    // issue ct1(mt) loads (consumed in cluster B, covered by cluster A)
#pragma unroll
    for (int kc = 0; kc < 3; ++kc) {
      i32x4 t = *(const i32x4*)(bp1 + kc * FRAG_B);
      b1[kc][0] = t[0]; b1[kc][1] = t[1]; b1[kc][2] = t[2]; b1[kc][3] = t[3];
    }
    bp1 += TSTRIDE;
    __builtin_amdgcn_sched_barrier(0);   // keep load issue above cluster A

    // ---- cluster A: ct0 MFMAs on pre (loaded one cluster ago; no wait) ----
    {
      f32x4 acc[4];
#pragma unroll
      for (int rt = 0; rt < 4; ++rt) acc[rt] = (f32x4){0.f, 0.f, 0.f, 0.f};
      __builtin_amdgcn_s_setprio(1);
#pragma unroll
      for (int kc = 0; kc < 3; ++kc)
#pragma unroll
        for (int rt = 0; rt < 4; ++rt)
          acc[rt] = __builtin_amdgcn_mfma_scale_f32_16x16x128_f8f6f4(
              afr[kc][rt], pre[kc], acc[rt], 4, 4,  // A fp4, B fp4
              0, 0x7b7b7b7b, 0, 0x7b7b7b7b);        // both scales 2^-4
      __builtin_amdgcn_s_setprio(0);
#pragma unroll
      for (int rt = 0; rt < 4; ++rt)
#pragma unroll
        for (int r = 0; r < 4; ++r)
          rmax[rt * 4 + r] = fmaxf(rmax[rt * 4 + r], acc[rt][r]);
    }
    __builtin_amdgcn_sched_barrier(0);   // cluster A stays above pre reload

    // issue ct0(mt+1) into pre (consumed next iter's cluster A)
    if (mt + 1 < MT_PER) {
#pragma unroll
      for (int kc = 0; kc < 3; ++kc) {
        i32x4 t = *(const i32x4*)(bp0 + kc * FRAG_B);
        pre[kc][0] = t[0]; pre[kc][1] = t[1];
        pre[kc][2] = t[2]; pre[kc][3] = t[3];
      }
      bp0 += TSTRIDE;
    }
    __builtin_amdgcn_sched_barrier(0);   // keep pre issue above cluster B

    // ---- cluster B: ct1 MFMAs on b1 -----------------------------------
    {
      f32x4 acc[4];
#pragma unroll
      for (int rt = 0; rt < 4; ++rt) acc[rt] = (f32x4){0.f, 0.f, 0.f, 0.f};
      __builtin_amdgcn_s_setprio(1);
#pragma unroll
      for (int kc = 0; kc < 3; ++kc)
#pragma unroll
        for (int rt = 0; rt < 4; ++rt)
          acc[rt] = __builtin_amdgcn_mfma_scale_f32_16x16x128_f8f6f4(
              afr[kc][rt], b1[kc], acc[rt], 4, 4,   // A fp4, B fp4
              0, 0x7b7b7b7b, 0, 0x7b7b7b7b);        // both scales 2^-4
      __builtin_amdgcn_s_setprio(0);
#pragma unroll
      for (int rt = 0; rt < 4; ++rt)
#pragma unroll
        for (int r = 0; r < 4; ++r)
          rmax[rt * 4 + r] = fmaxf(rmax[rt * 4 + r], acc[rt][r]);
    }
  }

#pragma unroll
  for (int i = 0; i < 16; ++i) {
    float v = rmax[i];
    v = fmaxf(v, __shfl_xor(v, 1));
    v = fmaxf(v, __shfl_xor(v, 2));
    v = fmaxf(v, __shfl_xor(v, 4));
    v = fmaxf(v, __shfl_xor(v, 8));
    rmax[i] = v;
  }
  if (l16 == 0) {
#pragma unroll
    for (int rt = 0; rt < 4; ++rt)
#pragma unroll
      for (int r = 0; r < 4; ++r)
        smax[wc][wr * 64 + rt * 16 + quad * 4 + r] = rmax[rt * 4 + r];
  }
  __syncthreads();
  if (tid < 128) {
    const float v = fmaxf(smax[0][tid], smax[1][tid]);
    pmax[(size_t)(qrow0 + tid) * NCHUNK + ychunk] = v;
  }
}

// ------- Kernel C: reduce partials; uniform row OR exact fp32 re-check -----
__global__ __launch_bounds__(256) void decide_kernel(
    const float* __restrict__ pmax, const float* __restrict__ qe,
    const float* __restrict__ me, const float* __restrict__ labels,
    float* __restrict__ out) {
  const int q = blockIdx.x;
  const int t = threadIdx.x;  // 256
  __shared__ float smx;
  if (t < 64) {
    float v = pmax[(size_t)q * NCHUNK + t];  // NCHUNK == 64
#pragma unroll
    for (int m = 1; m < 64; m <<= 1) v = fmaxf(v, __shfl_xor(v, m));
    if (t == 0) smx = v;
  }
  __syncthreads();
  if (smx <= 0.5f) {  // uniform fast path (expected for all queries)
    if (t < CN) out[(size_t)q * CN + t] = 1.0f / 128.0f;
    return;
  }
  // exact fp32 path (rare / borderline queries only)
  __shared__ float sred[256];
  __shared__ int sidx[256];
  __shared__ float wsum[4];
  const float* qr = qe + (size_t)q * DN;
  float ss = 0.f;
  for (int i = t; i < DN; i += 256) ss += qr[i] * qr[i];
#pragma unroll
  for (int m = 1; m < 64; m <<= 1) ss += __shfl_xor(ss, m);
  if ((t & 63) == 0) wsum[t >> 6] = ss;
  __syncthreads();
  const float qnorm = fmaxf(sqrtf(wsum[0] + wsum[1] + wsum[2] + wsum[3]), 1e-8f);

  float best = -3.0e38f;
  int bidx = 0x7fffffff;
  for (int j = t; j < MN; j += 256) {
    const float* mr = me + (size_t)j * DN;
    float dot = 0.f, ms = 0.f;
    for (int k = 0; k < DN; ++k) {
      float a = qr[k], b = mr[k];
      dot += a * b;
      ms += b * b;
    }
    const float sim = dot / (qnorm * fmaxf(sqrtf(ms), 1e-8f));
    if (sim > best) { best = sim; bidx = j; }  // strict > keeps first index
  }
  sred[t] = best;
  sidx[t] = bidx;
  __syncthreads();
  for (int s = 128; s > 0; s >>= 1) {
    if (t < s) {
      const float ov = sred[t + s];
      const int oi = sidx[t + s];
      if (ov > sred[t] || (ov == sred[t] && oi < sidx[t])) {
        sred[t] = ov;
        sidx[t] = oi;
      }
    }
    __syncthreads();
  }
  const float mx = sred[0];
  const int mi = sidx[0];
  if (t < CN)
    out[(size_t)q * CN + t] =
        (mx > 0.7f) ? labels[(size_t)mi * CN + t] : (1.0f / 128.0f);
}

extern "C" void kernel_launch(void* const* d_in, const int* in_sizes, int n_in,
                              void* d_out, int out_size, void* d_ws,
                              size_t ws_size, hipStream_t stream) {
  const float* qe = (const float*)d_in[0];  // [4096,384] f32
  const float* me = (const float*)d_in[1];  // [65536,384] f32
  const float* lb = (const float*)d_in[2];  // [65536,128] f32
  float* out = (float*)d_out;               // [4096,128] f32

  char* ws = (char*)d_ws;
  const size_t OFF_QN = 0;                  // qn4: 4096*192 = 786,432 B
  const size_t OFF_MN = OFF_QN + (size_t)QN * DN;        // mn4: 65536*192 B
  const size_t OFF_PMAX = OFF_MN + (size_t)MN * DN;      // (offsets roomy)
  unsigned char* qn4 = (unsigned char*)(ws + OFF_QN);    // fp4 fragment-major
  unsigned char* mn4 = (unsigned char*)(ws + OFF_MN);    // fp4 fragment-major
  float* pmax = (float*)(ws + OFF_PMAX);                 // [4096][64] = 1 MB

  nrm_kernel<<<(QN + MN) / 4, 256, 0, stream>>>(qe, me, qn4, mn4);
  gemm_max_kernel<<<dim3(QN / 128, NCHUNK), 256, 0, stream>>>(qn4, mn4, pmax);
  decide_kernel<<<QN, 256, 0, stream>>>(pmax, qe, me, lb, out);
}